// Round 2
// baseline (4987.851 us; speedup 1.0000x reference)
//
#include <hip/hip_runtime.h>
#include <hip/hip_bf16.h>

// VanillaRNN: S=512,B=256,E=256,H=1024,C=10, vocab=10
// Strategy:
//  - proj[v][h] = emb[v] @ W_hx + b_h  (10x1024, tiny)
//  - W_hh pre-packed to bf16 MFMA B-fragment layout (Wf), held in VGPRs
//  - persistent kernel: 16 batch-groups x 16 col-workgroups; per step:
//    group-local flag sync -> stage 16x1024 bf16 state tile (swizzled
//    global_load_lds) -> 32x mfma_f32_16x16x32_bf16 -> tanh -> store
//  - final: state_f32 @ W_ph + b_p

typedef __attribute__((ext_vector_type(8))) short short8;
typedef __attribute__((ext_vector_type(4))) float f32x4;

#define S_LEN 512
#define HDIM  1024
#define NVOC  10

// ws layout (bytes)
#define OFF_WF    0u          // 1024*1024 bf16 frag-packed = 2 MB
#define OFF_PROJ  2097152u    // 10*1024 f32 = 40960 B
#define OFF_STBF  2138112u    // 2 x 256*1024 bf16 = 1 MB (ping-pong)
#define OFF_STF   3186688u    // 256*1024 f32 = 1 MB
#define OFF_FLAGS 4235264u    // 16*512 u32 = 32 KB

__global__ void zero_flags_k(unsigned int* flags) {
    int id = blockIdx.x * 256 + threadIdx.x;
    if (id < 16 * S_LEN) flags[id] = 0u;
}

// proj[v][h] = sum_e emb[v][e]*W_hx[e][h] + b_h[h]
__global__ void proj_k(const float* __restrict__ emb, const float* __restrict__ W_hx,
                       const float* __restrict__ b_h, float* __restrict__ proj) {
    int id = blockIdx.x * 256 + threadIdx.x;
    if (id >= NVOC * HDIM) return;
    int v = id >> 10, h = id & 1023;
    float a = b_h[h];
    #pragma unroll 8
    for (int e = 0; e < 256; ++e) a += emb[v * 256 + e] * W_hx[e * HDIM + h];
    proj[id] = a;
}

static __device__ inline unsigned short f2bf(float f) {
    unsigned u = __builtin_bit_cast(unsigned, f);
    return (unsigned short)((u + 0x7fffu + ((u >> 16) & 1u)) >> 16);
}

// pack W_hh[k][n] (f32) -> Wf frag layout: [nt(64)][kk(32)][lane(64)][8] bf16
// lane l of (nt,kk) holds W[kk*32 + (l>>4)*8 + j][nt*16 + (l&15)]
__global__ void packw_k(const float* __restrict__ W_hh, unsigned short* __restrict__ Wf) {
    int idx = blockIdx.x * 256 + threadIdx.x;   // 131072 total
    int lane = idx & 63, kk = (idx >> 6) & 31, nt = idx >> 11;
    int k0 = kk * 32 + (lane >> 4) * 8;
    int col = nt * 16 + (lane & 15);
    unsigned short o[8];
    #pragma unroll
    for (int j = 0; j < 8; ++j) o[j] = f2bf(W_hh[(k0 + j) * HDIM + col]);
    short8 v;
    #pragma unroll
    for (int j = 0; j < 8; ++j) v[j] = (short)o[j];
    *(short8*)(Wf + (size_t)idx * 8) = v;
}

__global__ __launch_bounds__(256, 1) void rnn_steps_k(
    const int* __restrict__ x, const unsigned short* __restrict__ Wf,
    const float* __restrict__ proj, unsigned short* __restrict__ stbf,
    float* __restrict__ stf, unsigned int* __restrict__ flags)
{
    const int bid = blockIdx.x;
    // keep a group's 16 wgs on one XCD (bid%8 heuristic); bijective over 256
    const int g   = ((bid & 7) << 1) | ((bid >> 3) & 1);   // 0..15 batch-group
    const int wgn = bid >> 4;                              // 0..15 col-block
    const int tid = threadIdx.x;
    const int wave = tid >> 6, lane = tid & 63;
    const int b0 = g << 4;                 // batch row base
    const int nt = (wgn << 2) + wave;      // global 16-col tile index
    const int n0 = nt << 4;                // col base (per wave)
    const int wg_n0 = wgn << 6;            // col base (per workgroup)
    const int row = lane & 15;             // A-row / D-col lane index
    const int kl  = lane >> 4;             // k-group

    __shared__ __align__(16) char Abuf[32768];     // 16 x 1024 bf16 (swizzled)
    __shared__ unsigned char xl[S_LEN * 16];       // x slice for this group
    __shared__ float pl[NVOC * 64];                // proj slice for this wg

    for (int i = tid; i < S_LEN * 16; i += 256)
        xl[i] = (unsigned char)x[((i >> 4) << 8) + b0 + (i & 15)];
    // pl[v*64 + c] = proj[v][wg_n0 + c]  (c spans the wg's 64 cols)
    for (int i = tid; i < NVOC * 64; i += 256)
        pl[i] = proj[(i >> 6) * HDIM + wg_n0 + (i & 63)];

    // B fragments: wave's K=1024 x 16-col slice of W_hh, resident in VGPRs
    short8 bfr[32];
    const short8* wp = (const short8*)Wf;
    #pragma unroll
    for (int kk = 0; kk < 32; ++kk)
        bfr[kk] = wp[((nt << 5) + kk) * 64 + lane];

    __syncthreads();

    const int sw = (row & 7) << 4;   // XOR swizzle (bank-conflict fix)
    const int abase = row << 11;
    const int klb = kl << 4;

    for (int s = 0; s < S_LEN; ++s) {
        f32x4 acc0 = {0.f, 0.f, 0.f, 0.f};
        f32x4 acc1 = acc0, acc2 = acc0, acc3 = acc0;
        if (s > 0) {
            if (tid == 0) {
                const unsigned int* fp = flags + (g << 9) + (s - 1);
                while (__hip_atomic_load(fp, __ATOMIC_ACQUIRE, __HIP_MEMORY_SCOPE_AGENT) < 16u) {}
            }
            __syncthreads();
            // stage prev state tile (16 rows x 2048 B), source pre-swizzled so
            // linear LDS dest + swizzled ds_read agree (both-sides involution)
            const char* src = (const char*)stbf + (((s - 1) & 1) << 19) + (g << 15);
            #pragma unroll
            for (int it = 0; it < 8; ++it) {
                int o = (it * 256 + tid) * 16;
                int arow = o >> 11;
                int soff = (arow << 11) + ((o & 2047) ^ ((arow & 7) << 4));
                __builtin_amdgcn_global_load_lds(
                    (const __attribute__((address_space(1))) void*)(src + soff),
                    (__attribute__((address_space(3))) void*)(Abuf + it * 4096 + wave * 1024),
                    16, 0, 0);
            }
            __syncthreads();
            #pragma unroll
            for (int kk = 0; kk < 32; kk += 4) {   // 4 independent acc chains
                short8 a0 = *(const short8*)(Abuf + abase + ((((kk + 0) << 6) + klb) ^ sw));
                short8 a1 = *(const short8*)(Abuf + abase + ((((kk + 1) << 6) + klb) ^ sw));
                short8 a2 = *(const short8*)(Abuf + abase + ((((kk + 2) << 6) + klb) ^ sw));
                short8 a3 = *(const short8*)(Abuf + abase + ((((kk + 3) << 6) + klb) ^ sw));
                acc0 = __builtin_amdgcn_mfma_f32_16x16x32_bf16(a0, bfr[kk + 0], acc0, 0, 0, 0);
                acc1 = __builtin_amdgcn_mfma_f32_16x16x32_bf16(a1, bfr[kk + 1], acc1, 0, 0, 0);
                acc2 = __builtin_amdgcn_mfma_f32_16x16x32_bf16(a2, bfr[kk + 2], acc2, 0, 0, 0);
                acc3 = __builtin_amdgcn_mfma_f32_16x16x32_bf16(a3, bfr[kk + 3], acc3, 0, 0, 0);
            }
        }
        f32x4 accs = acc0 + acc1 + acc2 + acc3;
        #pragma unroll
        for (int j = 0; j < 4; ++j) {
            int r = (kl << 2) + j;                 // D row = batch-local row
            int xv = xl[(s << 4) + r];
            float p = pl[(xv << 6) + (wave << 4) + row];  // D col = wg_n0 + wave*16 + row
            float z = accs[j] + p;
            z = fminf(15.f, fmaxf(-15.f, z));
            float e = exp2f(z * 2.885390082f);     // e^(2z)
            float th = (e - 1.f) / (e + 1.f);      // tanh(z)
            if (s < S_LEN - 1) {
                stbf[((s & 1) << 18) + ((b0 + r) << 10) + n0 + row] = f2bf(th);
            } else {
                stf[((b0 + r) << 10) + n0 + row] = th;
            }
        }
        if (s < S_LEN - 1) {
            __syncthreads();  // drains all waves' stores (vmcnt0 before barrier)
            if (tid == 0)
                __hip_atomic_fetch_add(flags + (g << 9) + s, 1u,
                                       __ATOMIC_RELEASE, __HIP_MEMORY_SCOPE_AGENT);
        }
    }
}

// out[b][c] = state_f32[b] @ W_ph[:,c] + b_p[c]
__global__ void outproj_k(const float* __restrict__ stf, const float* __restrict__ W_ph,
                          const float* __restrict__ b_p, float* __restrict__ out) {
    int b = blockIdx.x, t = threadIdx.x;
    float acc[10];
    #pragma unroll
    for (int c = 0; c < 10; ++c) acc[c] = 0.f;
    for (int h = t; h < HDIM; h += 256) {
        float sv = stf[b * HDIM + h];
        const float* w = W_ph + h * 10;
        #pragma unroll
        for (int c = 0; c < 10; ++c) acc[c] += sv * w[c];
    }
    __shared__ float red[256][10];
    #pragma unroll
    for (int c = 0; c < 10; ++c) red[t][c] = acc[c];
    __syncthreads();
    for (int off = 128; off > 0; off >>= 1) {
        if (t < off) {
            #pragma unroll
            for (int c = 0; c < 10; ++c) red[t][c] += red[t + off][c];
        }
        __syncthreads();
    }
    if (t < 10) out[b * 10 + t] = red[0][t] + b_p[t];
}

extern "C" void kernel_launch(void* const* d_in, const int* in_sizes, int n_in,
                              void* d_out, int out_size, void* d_ws, size_t ws_size,
                              hipStream_t stream) {
    const int*   x    = (const int*)d_in[0];
    const float* emb  = (const float*)d_in[1];
    const float* W_hx = (const float*)d_in[2];
    const float* W_hh = (const float*)d_in[3];
    const float* W_ph = (const float*)d_in[4];
    const float* b_h  = (const float*)d_in[5];
    const float* b_p  = (const float*)d_in[6];

    char* ws = (char*)d_ws;
    unsigned short* Wf    = (unsigned short*)(ws + OFF_WF);
    float*          proj  = (float*)(ws + OFF_PROJ);
    unsigned short* stbf  = (unsigned short*)(ws + OFF_STBF);
    float*          stf   = (float*)(ws + OFF_STF);
    unsigned int*   flags = (unsigned int*)(ws + OFF_FLAGS);

    zero_flags_k<<<32, 256, 0, stream>>>(flags);
    proj_k<<<40, 256, 0, stream>>>(emb, W_hx, b_h, proj);
    packw_k<<<512, 256, 0, stream>>>(W_hh, Wf);
    rnn_steps_k<<<256, 256, 0, stream>>>(x, Wf, proj, stbf, stf, flags);
    outproj_k<<<256, 256, 0, stream>>>(stf, W_ph, b_p, (float*)d_out);
}